// Round 11
// baseline (2985.006 us; speedup 1.0000x reference)
//
#include <hip/hip_runtime.h>
#include <math.h>

#define TSTEPS 1024
#define HID    2048
#define IN_D   128
#define OUT_D  128
#define NWG    256
#define NTHR   512
#define NPAIRS (HID / 2)   // 1024 epoch-tagged 8B words per slot

#define LOG2PI_F 1.8378770664093453f

typedef unsigned long long u64;
typedef unsigned int       u32;

// round-to-nearest-even f32 -> bf16 (low 16 bits)
static __device__ __forceinline__ u32 bf16_rne(float f) {
    u32 u = __float_as_uint(f);
    return (u + 0x7FFFu + ((u >> 16) & 1u)) >> 16;
}
// fast transcendentals (v_exp_f32 + v_rcp_f32; ~1e-7 rel err vs 0.21 threshold)
static __device__ __forceinline__ float fast_sig(float x) {
    return __builtin_amdgcn_rcpf(1.0f + __expf(-x));
}
static __device__ __forceinline__ float fast_tanh(float x) {
    return 1.0f - 2.0f * __builtin_amdgcn_rcpf(1.0f + __expf(2.0f * x));
}

// ---------------------------------------------------------------------------
// Persistent LSTM rollout — r10 base (collective detection, u64 pkt =
// 2 x bf16 | tag32, slot parity, compact 32B publish) with three tail cuts:
//  1. Poll/stage split across waves 0 AND 1 (8 pairs/lane each): halves the
//     poll iteration period (discovery quantization) and the staging tail.
//  2. Raw u64 pairs staged to LDS; bf16 unpack happens inside the matvec
//     j-loop across all 512 threads (4 bit-ops per 16 FMA) instead of
//     serially on the polling wave.
//  3. Wave rg owns ALL 4 gate rows of cell 8w+rg (rows m*2048 + cell):
//     after its butterfly, lane 0 updates its cell in-wave (transcendentals
//     parallel across 8 waves, BEFORE sync2) and drops {f32 h, bf16 h} into
//     LDS. After sync2 wave-0 threads 0..3 only pack+store: 4 x u64 = 32B
//     publish burst + 32B f32 hs_out line (r7's scatter mistake avoided).
//
// Skew safety (unchanged): exact-match tags + slot parity. A WG publishes
// tag t+2 (overwriting tag t, same parity) only after its pollers consumed
// tag t+1 from ALL WGs, which required every WG to publish t+1, which
// required every WG's pollers to consume tag t. Induction from t=0 holds.
// ---------------------------------------------------------------------------
__global__ __launch_bounds__(NTHR)
void lstm_persist(const float* __restrict__ s0,
                  const float* __restrict__ Wih,
                  const float* __restrict__ Whh,
                  const float* __restrict__ bih,
                  const float* __restrict__ bhh,
                  float* __restrict__ hs_out,
                  u64* __restrict__ pairs)     // [2][NPAIRS]
{
    __shared__ __align__(16) u64 ldsP[2][NPAIRS];  // raw staged pairs, swizzled
    __shared__ __align__(16) u64 cellbuf[8];       // [wave]: lo = f32 h, hi = bf16 h

    const int tid   = threadIdx.x;
    const int wg    = blockIdx.x;
    const int hbase = wg * 8;
    const int rg    = tid >> 6;    // wave id 0..7
    const int lane  = tid & 63;
    const int cell  = hbase + rg;  // this wave's cell

    // ---- weights -> registers: rows m*2048+cell, k-slice [32*lane, +32) ----
    float w[4][32];
    float wih2[4][2];
    float breg[4];
#pragma unroll
    for (int m = 0; m < 4; ++m) {
        const int grow = m * HID + cell;
        const float4* src = (const float4*)(Whh + (size_t)grow * HID + lane * 32);
#pragma unroll
        for (int q = 0; q < 8; ++q) {
            float4 v = src[q];
            w[m][4*q+0] = v.x; w[m][4*q+1] = v.y;
            w[m][4*q+2] = v.z; w[m][4*q+3] = v.w;
        }
        wih2[m][0] = Wih[(size_t)grow * IN_D + 2 * lane];
        wih2[m][1] = Wih[(size_t)grow * IN_D + 2 * lane + 1];
        breg[m]    = bih[grow] + bhh[grow];
    }

    float c = 0.0f;   // cell state (lane 0 of each wave)

    for (int t = 0; t < TSTEPS; ++t) {
        const int slot = (t - 1) & 1;   // consumed slot (valid when t > 0)

        // ---- W_ih @ x_t partial (no h dependency) ----
        const float2 xv = *(const float2*)(s0 + (size_t)t * IN_D + 2 * lane);
        float acc[4];
#pragma unroll
        for (int m = 0; m < 4; ++m)
            acc[m] = wih2[m][0] * xv.x + wih2[m][1] * xv.y;

        // ---- collective detect + raw stage: waves 0 and 1, half each ----
        if (t > 0 && rg < 2) {
            const u32 want = (u32)t;
            const u64* base = pairs + (size_t)slot * NPAIRS + rg * 512;
            u64 v[8];
            for (;;) {
                int ok = 1;
#pragma unroll
                for (int j = 0; j < 8; ++j) {
                    v[j] = __hip_atomic_load(base + 64 * j + lane,
                                             __ATOMIC_RELAXED, __HIP_MEMORY_SCOPE_AGENT);
                    ok &= ((u32)(v[j] >> 32) == want);
                }
                if (__all(ok)) break;
                __builtin_amdgcn_s_sleep(1);
            }
            // store raw pairs, swizzled at 16B-chunk granularity
#pragma unroll
            for (int j = 0; j < 8; ++j) {
                const int idx  = rg * 512 + 64 * j + lane;  // pair index 0..1023
                const int cch  = idx >> 1;                  // 16B chunk 0..511
                const int p    = cch ^ ((cch >> 3) & 7);
                ldsP[slot][2 * p + (idx & 1)] = v[j];
            }
        }
        __syncthreads();   // sync1: ldsP staged

        // ---- recurrent matvec: 4 rows x 32 k, unpack-in-loop ----
        if (t > 0) {
#pragma unroll
            for (int j = 0; j < 8; ++j) {
                const int p = (8 * lane + j) ^ (lane & 7);
                const uint4 q = *(const uint4*)&ldsP[slot][2 * p];
                const float h0 = __uint_as_float(q.x << 16);
                const float h1 = __uint_as_float(q.x & 0xFFFF0000u);
                const float h2 = __uint_as_float(q.z << 16);
                const float h3 = __uint_as_float(q.z & 0xFFFF0000u);
#pragma unroll
                for (int m = 0; m < 4; ++m) {
                    acc[m] += h0 * w[m][4*j+0];
                    acc[m] += h1 * w[m][4*j+1];
                    acc[m] += h2 * w[m][4*j+2];
                    acc[m] += h3 * w[m][4*j+3];
                }
            }
        }

        // ---- full 64-lane butterfly: all 4 gate sums complete at lane 0 ----
#pragma unroll
        for (int m = 0; m < 4; ++m) {
            acc[m] += __shfl_xor(acc[m], 1);
            acc[m] += __shfl_xor(acc[m], 2);
            acc[m] += __shfl_xor(acc[m], 4);
            acc[m] += __shfl_xor(acc[m], 8);
            acc[m] += __shfl_xor(acc[m], 16);
            acc[m] += __shfl_xor(acc[m], 32);
        }

        // ---- in-wave cell update (parallel across 8 waves, pre-sync2) ----
        if (lane == 0) {
            const float ig = fast_sig (acc[0] + breg[0]);
            const float fg = fast_sig (acc[1] + breg[1]);
            const float gg = fast_tanh(acc[2] + breg[2]);
            const float og = fast_sig (acc[3] + breg[3]);
            c = fg * c + ig * gg;
            const float h = og * fast_tanh(c);
            cellbuf[rg] = ((u64)bf16_rne(h) << 32) | (u64)__float_as_uint(h);
        }
        __syncthreads();   // sync2: cellbuf ready

        // ---- pack + publish (threads 0..3 of wave 0; 32B bursts only) ----
        if (tid < 4) {
            const u64 cb0 = cellbuf[2 * tid];
            const u64 cb1 = cellbuf[2 * tid + 1];
            const u64 pair = (((u64)(u32)(t + 1)) << 32)
                           | (u64)(((u32)(cb0 >> 32)) | (((u32)(cb1 >> 32)) << 16));
            __hip_atomic_store(&pairs[(size_t)(t & 1) * NPAIRS + wg * 4 + tid], pair,
                               __ATOMIC_RELAXED, __HIP_MEMORY_SCOPE_AGENT);
            // f32 record for out_head: 4 lanes x float2 = 32B coalesced
            *(float2*)&hs_out[(size_t)t * HID + hbase + 2 * tid] =
                make_float2(__uint_as_float((u32)cb0), __uint_as_float((u32)cb1));
        }
    }
}

// ---------------------------------------------------------------------------
// Output head: mu/logvar GEMV + sample + logprob. Block = 4 timesteps.
// ---------------------------------------------------------------------------
__global__ __launch_bounds__(256)
void out_head(const float* __restrict__ eps,
              const float* __restrict__ Wmu,
              const float* __restrict__ bmu,
              const float* __restrict__ Wlv,
              const float* __restrict__ blv,
              const float* __restrict__ hs,
              float* __restrict__ xs,
              float* __restrict__ lp)
{
    __shared__ __align__(16) float hlds[4][HID];
    __shared__ __align__(16) float exch[4][256];

    const int tid = threadIdx.x;
    const int t0  = blockIdx.x * 4;

    {
        const float4* src = (const float4*)(hs + (size_t)t0 * HID);
        float4* dst = (float4*)&hlds[0][0];
#pragma unroll
        for (int i = 0; i < 8; ++i)
            dst[tid + i * 256] = src[tid + i * 256];
    }
    __syncthreads();

    const int  jrow  = tid & 127;
    const bool is_lv = tid >= 128;
    const float* Wrow = (is_lv ? Wlv : Wmu) + (size_t)jrow * HID;
    const float  bias = is_lv ? blv[jrow] : bmu[jrow];

    float acc[4] = {0.f, 0.f, 0.f, 0.f};
    const float4* w4 = (const float4*)Wrow;
#pragma unroll 4
    for (int kq = 0; kq < HID / 4; ++kq) {
        float4 wv = w4[kq];
#pragma unroll
        for (int tt = 0; tt < 4; ++tt) {
            float4 hv = ((const float4*)&hlds[tt][0])[kq];
            acc[tt] += wv.x * hv.x + wv.y * hv.y + wv.z * hv.z + wv.w * hv.w;
        }
    }
#pragma unroll
    for (int tt = 0; tt < 4; ++tt) exch[tt][tid] = acc[tt] + bias;
    __syncthreads();

#pragma unroll
    for (int r = 0; r < 2; ++r) {
        const int item = tid + r * 256;
        const int tt = item >> 7;
        const int jj = item & 127;
        const int t  = t0 + tt;
        const float mu = exch[tt][jj];
        const float lv = exch[tt][128 + jj];
        const float e  = eps[(size_t)t * OUT_D + jj];
        const float sd = expf(0.5f * lv);
        const float x  = mu + sd * e;
        const float d  = (x - mu) / sd;
        const float l  = -0.5f * d * d - 0.5f * lv - 0.5f * LOG2PI_F;
        xs[(size_t)t * OUT_D + jj] = x;
        lp[(size_t)t * OUT_D + jj] = l;
    }
}

// ---------------------------------------------------------------------------
extern "C" void kernel_launch(void* const* d_in, const int* in_sizes, int n_in,
                              void* d_out, int out_size, void* d_ws, size_t ws_size,
                              hipStream_t stream)
{
    (void)in_sizes; (void)n_in; (void)out_size; (void)ws_size;

    const float* s0  = (const float*)d_in[0];
    const float* eps = (const float*)d_in[1];
    const float* Wih = (const float*)d_in[2];
    const float* Whh = (const float*)d_in[3];
    const float* bih = (const float*)d_in[4];
    const float* bhh = (const float*)d_in[5];
    const float* Wmu = (const float*)d_in[6];
    const float* bmu = (const float*)d_in[7];
    const float* Wlv = (const float*)d_in[8];
    const float* blv = (const float*)d_in[9];

    float* out = (float*)d_out;
    float* xs = out;                         // [1024][128]
    float* lp = out + TSTEPS * OUT_D;        // [1024][128]
    float* hs = out + 2 * TSTEPS * OUT_D;    // [1024][2048]

    u64* pairs = (u64*)d_ws;                 // [2][1024] x 8B = 16KB

    // zero tags each launch (tag 0 matches no wanted tag >= 1)
    (void)hipMemsetAsync(d_ws, 0, 2 * NPAIRS * sizeof(u64), stream);

    hipLaunchKernelGGL(lstm_persist, dim3(NWG), dim3(NTHR), 0, stream,
                       s0, Wih, Whh, bih, bhh, hs, pairs);

    hipLaunchKernelGGL(out_head, dim3(TSTEPS / 4), dim3(256), 0, stream,
                       eps, Wmu, bmu, Wlv, blv, hs, xs, lp);
}

// Round 12
// 2947.316 us; speedup vs baseline: 1.0128x; 1.0128x over previous
//
#include <hip/hip_runtime.h>
#include <math.h>

#define TSTEPS 1024
#define HID    2048
#define IN_D   128
#define OUT_D  128
#define NWG    256
#define NTHR   512
#define NPAIRS (HID / 2)   // 1024 epoch-tagged 8B words per slot

#define LOG2PI_F 1.8378770664093453f

typedef unsigned long long u64;
typedef unsigned int       u32;

// round-to-nearest-even f32 -> bf16 (low 16 bits)
static __device__ __forceinline__ u32 bf16_rne(float f) {
    u32 u = __float_as_uint(f);
    return (u + 0x7FFFu + ((u >> 16) & 1u)) >> 16;
}
static __device__ __forceinline__ float bf16_lo(u32 payload) {
    return __uint_as_float(payload << 16);
}
static __device__ __forceinline__ float bf16_hi(u32 payload) {
    return __uint_as_float(payload & 0xFFFF0000u);
}
// fast transcendentals (v_exp_f32 + v_rcp_f32; ~1e-7 rel err vs 0.21 threshold)
static __device__ __forceinline__ float fast_sig(float x) {
    return __builtin_amdgcn_rcpf(1.0f + __expf(-x));
}
static __device__ __forceinline__ float fast_tanh(float x) {
    return 1.0f - 2.0f * __builtin_amdgcn_rcpf(1.0f + __expf(2.0f * x));
}

// ---------------------------------------------------------------------------
// Persistent LSTM rollout — best-of-all-rounds recombination:
//  * r6/r10 f32 ldsH staging + swizzle (conflict-light matvec: 6.7e7 not 2e8)
//  * detection split 8 ways: EVERY wave polls its own 128-pair slice
//    (2 pairs = 16B per lane; WG covers all 1024 pairs exactly once -> same
//    L3 poll traffic as r6). Wave exits on __all(2 tags match); unpack+stage
//    is 1 ds_write_b128 per lane, concurrent across all 8 waves.
//  * r11 producer tail: wave rg owns cell 8w+rg (rows m*2048+cell); after
//    its butterfly lane 0 updates the cell in-wave (transcendentals parallel
//    across waves, BEFORE sync2), drops {f32 h, bf16 h} into cellbuf; after
//    sync2 wave-0 threads 0..3 only pack + issue the 4 x u64 32B publish
//    burst + 32B f32 hs_out line (no scattered 4B stores — r7 lesson).
//
// Skew safety (unchanged r6 induction): exact-match tags + slot parity.
// A WG publishes tag t+2 (overwriting tag t, same parity slot) only after
// all its waves consumed tag t+1 from ALL WGs, which required every WG to
// have published t+1, which required every WG's waves to consume tag t.
// ---------------------------------------------------------------------------
__global__ __launch_bounds__(NTHR)
void lstm_persist(const float* __restrict__ s0,
                  const float* __restrict__ Wih,
                  const float* __restrict__ Whh,
                  const float* __restrict__ bih,
                  const float* __restrict__ bhh,
                  float* __restrict__ hs_out,
                  u64* __restrict__ pairs)     // [2][NPAIRS]
{
    __shared__ __align__(16) float4 ldsH[2][HID / 4];  // staged h, swizzled
    __shared__ __align__(16) u64    cellbuf[8];        // [wave]: lo=f32 h, hi=bf16 h

    const int tid   = threadIdx.x;
    const int wg    = blockIdx.x;
    const int hbase = wg * 8;
    const int rg    = tid >> 6;    // wave id 0..7
    const int lane  = tid & 63;
    const int cell  = hbase + rg;  // this wave's cell

    // ---- weights -> registers: rows m*2048+cell, k-slice [32*lane, +32) ----
    float w[4][32];
    float wih2[4][2];
    float breg[4];
#pragma unroll
    for (int m = 0; m < 4; ++m) {
        const int grow = m * HID + cell;
        const float4* src = (const float4*)(Whh + (size_t)grow * HID + lane * 32);
#pragma unroll
        for (int q = 0; q < 8; ++q) {
            float4 v = src[q];
            w[m][4*q+0] = v.x; w[m][4*q+1] = v.y;
            w[m][4*q+2] = v.z; w[m][4*q+3] = v.w;
        }
        wih2[m][0] = Wih[(size_t)grow * IN_D + 2 * lane];
        wih2[m][1] = Wih[(size_t)grow * IN_D + 2 * lane + 1];
        breg[m]    = bih[grow] + bhh[grow];
    }

    float c = 0.0f;   // cell state (lane 0 of each wave)

    for (int t = 0; t < TSTEPS; ++t) {
        const int slot = (t - 1) & 1;   // consumed slot (valid when t > 0)

        // ---- W_ih @ x_t partial (no h dependency) ----
        const float2 xv = *(const float2*)(s0 + (size_t)t * IN_D + 2 * lane);
        float acc[4];
#pragma unroll
        for (int m = 0; m < 4; ++m)
            acc[m] = wih2[m][0] * xv.x + wih2[m][1] * xv.y;

        // ---- per-wave collective detect + stage: wave rg owns 128 pairs ----
        if (t > 0) {
            const u32 want = (u32)t;
            const u64* sp = pairs + (size_t)slot * NPAIRS + rg * 128 + 2 * lane;
            u64 q0, q1;
            for (;;) {
                q0 = __hip_atomic_load(sp,     __ATOMIC_RELAXED, __HIP_MEMORY_SCOPE_AGENT);
                q1 = __hip_atomic_load(sp + 1, __ATOMIC_RELAXED, __HIP_MEMORY_SCOPE_AGENT);
                const int ok = ((u32)(q0 >> 32) == want) & ((u32)(q1 >> 32) == want);
                if (__all(ok)) break;
                __builtin_amdgcn_s_sleep(1);
            }
            // unpack 2 pairs -> 4 f32, one b128 write, swizzled chunk
            float4 hv;
            hv.x = bf16_lo((u32)q0);
            hv.y = bf16_hi((u32)q0);
            hv.z = bf16_lo((u32)q1);
            hv.w = bf16_hi((u32)q1);
            const int cch = rg * 64 + lane;            // 16B chunk 0..511
            ldsH[slot][cch ^ ((cch >> 3) & 7)] = hv;
        }
        __syncthreads();   // sync1: ldsH staged

        // ---- recurrent matvec: 4 rows x 32 k per thread (f32, conflict-light) ----
        if (t > 0) {
#pragma unroll
            for (int j = 0; j < 8; ++j) {
                const int p = (8 * lane + j) ^ (lane & 7);
                float4 hv = ldsH[slot][p];
#pragma unroll
                for (int m = 0; m < 4; ++m) {
                    acc[m] += hv.x * w[m][4*j+0];
                    acc[m] += hv.y * w[m][4*j+1];
                    acc[m] += hv.z * w[m][4*j+2];
                    acc[m] += hv.w * w[m][4*j+3];
                }
            }
        }

        // ---- full 64-lane butterfly: all 4 gate sums complete at lane 0 ----
#pragma unroll
        for (int m = 0; m < 4; ++m) {
            acc[m] += __shfl_xor(acc[m], 1);
            acc[m] += __shfl_xor(acc[m], 2);
            acc[m] += __shfl_xor(acc[m], 4);
            acc[m] += __shfl_xor(acc[m], 8);
            acc[m] += __shfl_xor(acc[m], 16);
            acc[m] += __shfl_xor(acc[m], 32);
        }

        // ---- in-wave cell update (parallel across 8 waves, pre-sync2) ----
        if (lane == 0) {
            const float ig = fast_sig (acc[0] + breg[0]);
            const float fg = fast_sig (acc[1] + breg[1]);
            const float gg = fast_tanh(acc[2] + breg[2]);
            const float og = fast_sig (acc[3] + breg[3]);
            c = fg * c + ig * gg;
            const float h = og * fast_tanh(c);
            cellbuf[rg] = ((u64)bf16_rne(h) << 32) | (u64)__float_as_uint(h);
        }
        __syncthreads();   // sync2: cellbuf ready

        // ---- pack + publish (threads 0..3 of wave 0; 32B bursts only) ----
        if (tid < 4) {
            const u64 cb0 = cellbuf[2 * tid];
            const u64 cb1 = cellbuf[2 * tid + 1];
            const u64 pair = (((u64)(u32)(t + 1)) << 32)
                           | (u64)(((u32)(cb0 >> 32)) | (((u32)(cb1 >> 32)) << 16));
            __hip_atomic_store(&pairs[(size_t)(t & 1) * NPAIRS + wg * 4 + tid], pair,
                               __ATOMIC_RELAXED, __HIP_MEMORY_SCOPE_AGENT);
            // f32 record for out_head: 4 lanes x float2 = 32B coalesced
            *(float2*)&hs_out[(size_t)t * HID + hbase + 2 * tid] =
                make_float2(__uint_as_float((u32)cb0), __uint_as_float((u32)cb1));
        }
    }
}

// ---------------------------------------------------------------------------
// Output head: mu/logvar GEMV + sample + logprob. Block = 4 timesteps.
// ---------------------------------------------------------------------------
__global__ __launch_bounds__(256)
void out_head(const float* __restrict__ eps,
              const float* __restrict__ Wmu,
              const float* __restrict__ bmu,
              const float* __restrict__ Wlv,
              const float* __restrict__ blv,
              const float* __restrict__ hs,
              float* __restrict__ xs,
              float* __restrict__ lp)
{
    __shared__ __align__(16) float hlds[4][HID];
    __shared__ __align__(16) float exch[4][256];

    const int tid = threadIdx.x;
    const int t0  = blockIdx.x * 4;

    {
        const float4* src = (const float4*)(hs + (size_t)t0 * HID);
        float4* dst = (float4*)&hlds[0][0];
#pragma unroll
        for (int i = 0; i < 8; ++i)
            dst[tid + i * 256] = src[tid + i * 256];
    }
    __syncthreads();

    const int  jrow  = tid & 127;
    const bool is_lv = tid >= 128;
    const float* Wrow = (is_lv ? Wlv : Wmu) + (size_t)jrow * HID;
    const float  bias = is_lv ? blv[jrow] : bmu[jrow];

    float acc[4] = {0.f, 0.f, 0.f, 0.f};
    const float4* w4 = (const float4*)Wrow;
#pragma unroll 4
    for (int kq = 0; kq < HID / 4; ++kq) {
        float4 wv = w4[kq];
#pragma unroll
        for (int tt = 0; tt < 4; ++tt) {
            float4 hv = ((const float4*)&hlds[tt][0])[kq];
            acc[tt] += wv.x * hv.x + wv.y * hv.y + wv.z * hv.z + wv.w * hv.w;
        }
    }
#pragma unroll
    for (int tt = 0; tt < 4; ++tt) exch[tt][tid] = acc[tt] + bias;
    __syncthreads();

#pragma unroll
    for (int r = 0; r < 2; ++r) {
        const int item = tid + r * 256;
        const int tt = item >> 7;
        const int jj = item & 127;
        const int t  = t0 + tt;
        const float mu = exch[tt][jj];
        const float lv = exch[tt][128 + jj];
        const float e  = eps[(size_t)t * OUT_D + jj];
        const float sd = expf(0.5f * lv);
        const float x  = mu + sd * e;
        const float d  = (x - mu) / sd;
        const float l  = -0.5f * d * d - 0.5f * lv - 0.5f * LOG2PI_F;
        xs[(size_t)t * OUT_D + jj] = x;
        lp[(size_t)t * OUT_D + jj] = l;
    }
}

// ---------------------------------------------------------------------------
extern "C" void kernel_launch(void* const* d_in, const int* in_sizes, int n_in,
                              void* d_out, int out_size, void* d_ws, size_t ws_size,
                              hipStream_t stream)
{
    (void)in_sizes; (void)n_in; (void)out_size; (void)ws_size;

    const float* s0  = (const float*)d_in[0];
    const float* eps = (const float*)d_in[1];
    const float* Wih = (const float*)d_in[2];
    const float* Whh = (const float*)d_in[3];
    const float* bih = (const float*)d_in[4];
    const float* bhh = (const float*)d_in[5];
    const float* Wmu = (const float*)d_in[6];
    const float* bmu = (const float*)d_in[7];
    const float* Wlv = (const float*)d_in[8];
    const float* blv = (const float*)d_in[9];

    float* out = (float*)d_out;
    float* xs = out;                         // [1024][128]
    float* lp = out + TSTEPS * OUT_D;        // [1024][128]
    float* hs = out + 2 * TSTEPS * OUT_D;    // [1024][2048]

    u64* pairs = (u64*)d_ws;                 // [2][1024] x 8B = 16KB

    // zero tags each launch (tag 0 matches no wanted tag >= 1)
    (void)hipMemsetAsync(d_ws, 0, 2 * NPAIRS * sizeof(u64), stream);

    hipLaunchKernelGGL(lstm_persist, dim3(NWG), dim3(NTHR), 0, stream,
                       s0, Wih, Whh, bih, bhh, hs, pairs);

    hipLaunchKernelGGL(out_head, dim3(TSTEPS / 4), dim3(256), 0, stream,
                       eps, Wmu, bmu, Wlv, blv, hs, xs, lp);
}